// Round 9
// baseline (133.646 us; speedup 1.0000x reference)
//
#include <hip/hip_runtime.h>

// QueryEncDec: 2 stacks x 128 layers of scalar GRU (H=in=1), T=256.
// R9: 2 waves x 64 lanes; lane j of wave w owns layers 128w+2j (A) and
// 128w+2j+1 (B), software-pipelined with lane-lag 2:
//   iteration i: A at tA=i-2j, B at tB=i-2j-1.
//   xA = lane j-1's hcB from iter i-1 (DPP wave_shr:1, old-operand = feed)
//   xB = own hcA from iter i-1 (register)
// => the two cells per iteration are INDEPENDENT; their ~150-cy chains
// interleave on the SIMD, so per-iteration latency ~ one cell chain while the
// wave spans 128 layers. Only ONE cross-wave boundary (layer 127->128) via
// the proven tagged-LDS mailbox, now with true prefetch: next batch's
// ds_read_b64 is issued 8 iterations before its validation (latency hidden).
// Producer (wave 0) collects lane-63 hB history via DPP wave_shl:1 and
// flushes 8 tagged slots per 8 iters; consumer (wave 1) pre-spins once to
// lag ~158. Wave 1's collector goes to global (dec_out). Cell math identical
// to R7/R8 (constants folded; absmax was 0.0).

#define T_LEN 256
typedef unsigned long long u64;
typedef unsigned int u32;

__device__ __forceinline__ float fexp2(float x) { return __builtin_amdgcn_exp2f(x); }
__device__ __forceinline__ float frcp(float x)  { return __builtin_amdgcn_rcpf(x); }

struct CellW {
    float wri, wrh, brc;   // r gate, pre-scaled by -log2(e)
    float wzi, wzh, bzc;   // z gate, pre-scaled by -log2(e)
    float wni, bni;        // n gate input half, pre-scaled by 2*log2(e)
    float wnh, bnh;        // n gate hidden half, pre-scaled by 2*log2(e)
};

__device__ __forceinline__ float cell_step(const CellW& c, float x, float h) {
    const float xr  = __builtin_fmaf(c.wri, x, c.brc);
    const float xz  = __builtin_fmaf(c.wzi, x, c.bzc);
    const float gin = __builtin_fmaf(c.wni, x, c.bni);
    const float ghn = __builtin_fmaf(c.wnh, h, c.bnh);
    const float er  = fexp2(__builtin_fmaf(c.wrh, h, xr));
    const float ez  = fexp2(__builtin_fmaf(c.wzh, h, xz));
    const float r   = frcp(1.0f + er);
    const float z   = frcp(1.0f + ez);
    const float en  = fexp2(__builtin_fmaf(r, ghn, gin));   // e^{2v}
    const float q   = frcp(1.0f + en);                      // n = 1-2q
    const float A   = __builtin_fmaf(z, h - 1.0f, 1.0f);
    const float B   = __builtin_fmaf(2.0f, z, -2.0f);
    return __builtin_fmaf(q, B, A);                         // (1-z)n + z h
}

template<bool LAST>
__device__ __forceinline__ void run_wave2(
    const int j, const CellW& cA, const CellW& cB,
    volatile u64* inbox, volatile u64* outbox,
    float* __restrict__ out, float* __restrict__ dumpG,
    float& hA_out, float& hB_out)
{
    float hA = 0.0f, hB = 0.0f;
    float hcA_prev = 0.0f, hcB_prev = 0.0f;
    u32 coll = 0;                       // lane m: lane-63 hB from (63-m) iters ago
    const int js = j & 7;

    // pre-spin: slot 31 (tag 32) is flushed at producer iter ~158 -> lag ~158,
    // 16+ iters of slack over the ~142 required. Wave 0 (X box) passes now.
    {
        u64 v = inbox[31];
        while (__ballot((u32)(v >> 32) == 32u) != ~0ull) v = inbox[31];
    }
    u64 bnext = inbox[js];              // prefetch batch 0

    #pragma unroll 1
    for (int b = 0; b < 48; ++b) {      // 48 x 8 = 384 iterations
        const int s0 = b * 8;
        u32 bval = 0;
        if (s0 < T_LEN) {               // uniform
            const int slot = s0 + js;
            u64 v = bnext;              // issued 8 iterations ago -> no stall
            while (__ballot((u32)(v >> 32) == (u32)(slot + 1)) != ~0ull)
                v = inbox[slot];        // cold fallback (fill only)
            bval = (u32)v;
            if (s0 + 8 < T_LEN) bnext = inbox[s0 + 8 + js]; // prefetch next
        }
        #pragma unroll
        for (int si = 0; si < 8; ++si) {
            const int i = s0 + si;
            // feed value for lane 0 (batch-lane si holds slot s0+si)
            const int fv = __builtin_amdgcn_readlane((int)bval, si);
            // xA: lane j <- lane j-1's hcB_prev; lane 0 <- feed (DPP old)
            const int xm = __builtin_amdgcn_update_dpp(
                fv, __builtin_bit_cast(int, hcB_prev),
                0x138 /*wave_shr:1*/, 0xF, 0xF, false);
            const float xA = __builtin_bit_cast(float, xm);
            const float xB = hcA_prev;  // own A candidate from prev iteration

            const float hcA = cell_step(cA, xA, hA);
            const float hcB = cell_step(cB, xB, hB);

            const int tA = i - 2 * j;
            const int tB = tA - 1;
            hA = ((u32)tA < (u32)T_LEN) ? hcA : hA;
            hB = ((u32)tB < (u32)T_LEN) ? hcB : hB;
            hcA_prev = hcA;
            hcB_prev = hcB;

            // collector: shift history DOWN (lane m <- m+1), insert committed hB
            const int cs = __builtin_amdgcn_update_dpp(
                0, (int)coll, 0x130 /*wave_shl:1*/, 0xF, 0xF, false);
            coll = (j == 63) ? __builtin_bit_cast(u32, hB) : (u32)cs;

            if (si == 6) {              // flush: lanes 56..63 hold t = i+m-190
                const int  tm   = i + j - 190;
                const bool real = (j >= 56) & (tm >= 0);   // tm <= 255 by design
                if (!LAST) {
                    const int widx = real ? tm : (T_LEN + j);  // dump: 256+j
                    outbox[widx] = ((u64)(u32)(tm + 1) << 32) | (u64)coll;
                } else {                // dec_out: coalesced 8-float store
                    float* p = real ? (out + tm) : (dumpG + j);
                    *p = __builtin_bit_cast(float, coll);
                }
            }
        }
    }
    hA_out = hA;
    hB_out = hB;
}

__global__ __launch_bounds__(128, 1) void gru_pipe9(
    const float* __restrict__ X,
    const float* __restrict__ enc_w_ih, const float* __restrict__ enc_w_hh,
    const float* __restrict__ enc_b_ih, const float* __restrict__ enc_b_hh,
    const float* __restrict__ dec_w_ih, const float* __restrict__ dec_w_hh,
    const float* __restrict__ dec_b_ih, const float* __restrict__ dec_b_hh,
    float* __restrict__ out, float* __restrict__ dumpG)
{
    const int tid = threadIdx.x;        // 0..127
    const int w   = tid >> 6;           // wave 0..1
    const int j   = tid & 63;

    __shared__ u64 xsM[T_LEN];          // X as a pre-tagged mailbox
    __shared__ u64 box[T_LEN + 64];     // boundary mailbox + 64 dump slots

    xsM[tid]       = ((u64)(u32)(tid + 1) << 32) |
                     (u64)__builtin_bit_cast(u32, X[tid]);
    xsM[tid + 128] = ((u64)(u32)(tid + 129) << 32) |
                     (u64)__builtin_bit_cast(u32, X[tid + 128]);
    box[tid]       = 0ull;              // data slots need tag=0
    box[tid + 128] = 0ull;

    // lane j of wave w: layers 128w+2j (A), 128w+2j+1 (B); both in one stack
    const float* wip = (w == 0) ? enc_w_ih : dec_w_ih;
    const float* whp = (w == 0) ? enc_w_hh : dec_w_hh;
    const float* bip = (w == 0) ? enc_b_ih : dec_b_ih;
    const float* bhp = (w == 0) ? enc_b_hh : dec_b_hh;
    const float L2E = 1.44269504088896340736f;

    CellW cc[2];
    #pragma unroll
    for (int k = 0; k < 2; ++k) {
        const int pl = 2 * j + k;       // 0..127 within the stack
        cc[k].wri = -L2E * wip[3 * pl + 0];
        cc[k].wrh = -L2E * whp[3 * pl + 0];
        cc[k].brc = -L2E * (bip[3 * pl + 0] + bhp[3 * pl + 0]);
        cc[k].wzi = -L2E * wip[3 * pl + 1];
        cc[k].wzh = -L2E * whp[3 * pl + 1];
        cc[k].bzc = -L2E * (bip[3 * pl + 1] + bhp[3 * pl + 1]);
        cc[k].wni = 2.0f * L2E * wip[3 * pl + 2];
        cc[k].bni = 2.0f * L2E * bip[3 * pl + 2];
        cc[k].wnh = 2.0f * L2E * whp[3 * pl + 2];
        cc[k].bnh = 2.0f * L2E * bhp[3 * pl + 2];
    }

    __syncthreads();                    // the only block barrier

    float hA, hB;
    if (w == 0) {
        run_wave2<false>(j, cc[0], cc[1], xsM, box, out, dumpG, hA, hB);
    } else {
        run_wave2<true >(j, cc[0], cc[1], box, box /*unused*/, out, dumpG, hA, hB);
        // dec_h: layers 128+2j, 129+2j
        out[T_LEN + 2 * j]     = hA;
        out[T_LEN + 2 * j + 1] = hB;
    }
}

extern "C" void kernel_launch(void* const* d_in, const int* in_sizes, int n_in,
                              void* d_out, int out_size, void* d_ws, size_t ws_size,
                              hipStream_t stream) {
    const float* X        = (const float*)d_in[0];
    const float* enc_w_ih = (const float*)d_in[1];
    const float* enc_w_hh = (const float*)d_in[2];
    const float* enc_b_ih = (const float*)d_in[3];
    const float* enc_b_hh = (const float*)d_in[4];
    const float* dec_w_ih = (const float*)d_in[5];
    const float* dec_w_hh = (const float*)d_in[6];
    const float* dec_b_ih = (const float*)d_in[7];
    const float* dec_b_hh = (const float*)d_in[8];
    float* out = (float*)d_out;
    float* dumpG = (float*)d_ws;

    gru_pipe9<<<1, 128, 0, stream>>>(X,
                                     enc_w_ih, enc_w_hh, enc_b_ih, enc_b_hh,
                                     dec_w_ih, dec_w_hh, dec_b_ih, dec_b_hh,
                                     out, dumpG);
}

// Round 10
// 107.624 us; speedup vs baseline: 1.2418x; 1.2418x over previous
//
#include <hip/hip_runtime.h>

// QueryEncDec: 2 stacks x 128 layers of scalar GRU (H=in=1), T=256.
// R10 = R8 structure (4 waves x 64 lanes, 1 layer/lane -- best measured) with
// three latency trims:
//  1. Three-phase loop: prologue (s<64, commit-masked) / steady (64..255,
//     NO commit cndmask or t-compare -- all lanes provably in [0,255]) /
//     epilogue (>=256, masked, no mailbox reads).
//  2. fma rebalance: the DPP-delivered x enters ONE fma before exp2
//     (er = exp2(fma(wri,x, fma(wrh,h,brc)))) -- shortens the x->hc chain.
//  3. Producer flushes every 4 steps (lanes 60..63, collector depth 4):
//     publication delay 70->66, pre-spin lag 78->74, path 554->542 steps.
// Handoff: single DPP wave_shr:1, old-operand = lane-0 feed (R8-proven).
// Cross-wave mailbox: tagged u64 slots, batch-8 reads + one __ballot,
// collector via DPP wave_shl:1 (R7-proven). Cell math identical to R8.

#define T_LEN 256
#define MBOX  320              // 0..255 data slots, 256..319 per-lane dump
typedef unsigned long long u64;
typedef unsigned int u32;

__device__ __forceinline__ float fexp2(float x) { return __builtin_amdgcn_exp2f(x); }
__device__ __forceinline__ float frcp(float x)  { return __builtin_amdgcn_rcpf(x); }

struct CellW {
    float wri, wrh, brc;   // r gate, pre-scaled by -log2(e)
    float wzi, wzh, bzc;   // z gate, pre-scaled by -log2(e)
    float wni, bni;        // n gate input half, pre-scaled by 2*log2(e)
    float wnh, bnh;        // n gate hidden half, pre-scaled by 2*log2(e)
};

__device__ __forceinline__ float cell_step(const CellW& c, float x, float h) {
    // h-leg pre-sums run while x is still in the DPP; x enters 1 fma deep.
    const float hr  = __builtin_fmaf(c.wrh, h, c.brc);
    const float hz  = __builtin_fmaf(c.wzh, h, c.bzc);
    const float ghn = __builtin_fmaf(c.wnh, h, c.bnh);
    const float gin = __builtin_fmaf(c.wni, x, c.bni);
    const float er  = fexp2(__builtin_fmaf(c.wri, x, hr));
    const float ez  = fexp2(__builtin_fmaf(c.wzi, x, hz));
    const float r   = frcp(1.0f + er);
    const float z   = frcp(1.0f + ez);
    const float en  = fexp2(__builtin_fmaf(r, ghn, gin));   // e^{2v}
    const float q   = frcp(1.0f + en);                      // n = 1-2q
    const float A   = __builtin_fmaf(z, h - 1.0f, 1.0f);
    const float B   = __builtin_fmaf(2.0f, z, -2.0f);
    return __builtin_fmaf(q, B, A);                         // (1-z)n + z h
}

template<bool MASKED, bool READ, bool LAST>
__device__ __forceinline__ void do_batch(
    const int s0, const int j, const int js, const CellW& c,
    volatile u64* inbox, volatile u64* outbox,
    float* __restrict__ out, float* __restrict__ dumpG,
    float& h, float& hcp, u32& coll)
{
    u32 bval = 0;
    if (READ) {                         // one ds_read_b64 + one ballot / 8 steps
        const int slot = s0 + js;
        u64 v = inbox[slot];
        while (__ballot((u32)(v >> 32) == (u32)(slot + 1)) != ~0ull)
            v = inbox[slot];            // fallback; first-try pass in steady state
        bval = (u32)v;
    }
    #pragma unroll
    for (int si = 0; si < 8; ++si) {
        const int s = s0 + si;
        // lane-0 feed (literal-index readlane); handoff via DPP old-operand
        const int fv = READ ? __builtin_amdgcn_readlane((int)bval, si) : 0;
        const int xm = __builtin_amdgcn_update_dpp(
            fv, __builtin_bit_cast(int, hcp), 0x138 /*wave_shr:1*/, 0xF, 0xF, false);
        const float x = __builtin_bit_cast(float, xm);

        const float hc = cell_step(c, x, h);
        if (MASKED) {
            const int t = s - j;
            h = ((u32)t < (u32)T_LEN) ? hc : h;
        } else {
            h = hc;                     // steady: always in-range, no cndmask
        }
        hcp = hc;

        // collector: shift history DOWN (lane m <- m+1), insert committed h
        const int cs = __builtin_amdgcn_update_dpp(
            0, (int)coll, 0x130 /*wave_shl:1*/, 0xF, 0xF, false);
        coll = (j == 63) ? __builtin_bit_cast(u32, h) : (u32)cs;

        if (si == 2 || si == 6) {       // flush every 4 steps (compile-time)
            // lane m in 60..63 holds lane-63 h for t = s + m - 126
            const int  tm   = s + j - 126;
            const bool real = (j >= 60) & (tm >= 0);
            if (!LAST) {
                const int widx = real ? tm : (T_LEN + j);    // dump: 256+j
                outbox[widx] = ((u64)(u32)(tm + 1) << 32) | (u64)coll;
            } else {                    // dec_out: coalesced 4-float store
                float* p = real ? (out + tm) : (dumpG + j);
                *p = __builtin_bit_cast(float, coll);
            }
        }
    }
}

template<bool LAST>
__device__ __forceinline__ float run_wave(
    const int j, const CellW& c,
    volatile u64* inbox, volatile u64* outbox,
    float* __restrict__ out, float* __restrict__ dumpG)
{
    float h = 0.0f, hcp = 0.0f;
    u32 coll = 0;
    const int js = j & 7;

    // pre-spin: slot 11 (tag 12) is published at producer local step 74 ->
    // lag >= 74; batch s0 needs slot s0+7 by step s0+73 -> first-try passes.
    // Wave 0's inbox is the pre-tagged X mailbox: passes immediately.
    {
        u64 v = inbox[11];
        while (__ballot((u32)(v >> 32) == 12u) != ~0ull) v = inbox[11];
    }

    #pragma unroll 1
    for (int b = 0; b < 8; ++b)         // prologue: s = 0..63 (masked, reads)
        do_batch<true, true, LAST>(b * 8, j, js, c, inbox, outbox, out, dumpG, h, hcp, coll);
    #pragma unroll 1
    for (int b = 8; b < 32; ++b)        // steady: s = 64..255 (unmasked, reads)
        do_batch<false, true, LAST>(b * 8, j, js, c, inbox, outbox, out, dumpG, h, hcp, coll);
    #pragma unroll 1
    for (int b = 32; b < 40; ++b)       // epilogue: s = 256..319 (masked, no reads)
        do_batch<true, false, LAST>(b * 8, j, js, c, inbox, outbox, out, dumpG, h, hcp, coll);

    return h;
}

__global__ __launch_bounds__(256, 1) void gru_pipe10(
    const float* __restrict__ X,
    const float* __restrict__ enc_w_ih, const float* __restrict__ enc_w_hh,
    const float* __restrict__ enc_b_ih, const float* __restrict__ enc_b_hh,
    const float* __restrict__ dec_w_ih, const float* __restrict__ dec_w_hh,
    const float* __restrict__ dec_b_ih, const float* __restrict__ dec_b_hh,
    float* __restrict__ out, float* __restrict__ dumpG)
{
    const int tid = threadIdx.x;        // global layer 0..255
    const int w   = tid >> 6;           // wave 0..3
    const int j   = tid & 63;

    __shared__ u64 xsM[T_LEN];          // X as a pre-tagged mailbox
    __shared__ u64 box[4][MBOX];        // box[3] = wave-3 trash (uniform code path)

    xsM[tid] = ((u64)(u32)(tid + 1) << 32) |
               (u64)__builtin_bit_cast(u32, X[tid]);
    box[0][tid] = 0ull;                 // data slots 0..255 need tag=0
    box[1][tid] = 0ull;
    box[2][tid] = 0ull;
    box[3][tid] = 0ull;

    // per-layer params (torch gate order r,z,n), constants folded
    const int pl = tid & 127;
    const float* wip = (tid < 128) ? enc_w_ih : dec_w_ih;
    const float* whp = (tid < 128) ? enc_w_hh : dec_w_hh;
    const float* bip = (tid < 128) ? enc_b_ih : dec_b_ih;
    const float* bhp = (tid < 128) ? enc_b_hh : dec_b_hh;
    const float L2E = 1.44269504088896340736f;
    CellW c;
    c.wri = -L2E * wip[3 * pl + 0];
    c.wrh = -L2E * whp[3 * pl + 0];
    c.brc = -L2E * (bip[3 * pl + 0] + bhp[3 * pl + 0]);
    c.wzi = -L2E * wip[3 * pl + 1];
    c.wzh = -L2E * whp[3 * pl + 1];
    c.bzc = -L2E * (bip[3 * pl + 1] + bhp[3 * pl + 1]);
    c.wni = 2.0f * L2E * wip[3 * pl + 2];
    c.bni = 2.0f * L2E * bip[3 * pl + 2];
    c.wnh = 2.0f * L2E * whp[3 * pl + 2];
    c.bnh = 2.0f * L2E * bhp[3 * pl + 2];

    __syncthreads();                    // the only block barrier

    volatile u64* inbox  = (w == 0) ? xsM : box[w - 1];
    volatile u64* outbox = box[w];

    float h;
    if (w == 3) h = run_wave<true >(j, c, inbox, outbox, out, dumpG);
    else        h = run_wave<false>(j, c, inbox, outbox, out, dumpG);

    // dec_h: final hidden of decoder layers (global layers 128..255)
    if (w >= 2) out[T_LEN + 64 * (w - 2) + j] = h;
}

extern "C" void kernel_launch(void* const* d_in, const int* in_sizes, int n_in,
                              void* d_out, int out_size, void* d_ws, size_t ws_size,
                              hipStream_t stream) {
    const float* X        = (const float*)d_in[0];
    const float* enc_w_ih = (const float*)d_in[1];
    const float* enc_w_hh = (const float*)d_in[2];
    const float* enc_b_ih = (const float*)d_in[3];
    const float* enc_b_hh = (const float*)d_in[4];
    const float* dec_w_ih = (const float*)d_in[5];
    const float* dec_w_hh = (const float*)d_in[6];
    const float* dec_b_ih = (const float*)d_in[7];
    const float* dec_b_hh = (const float*)d_in[8];
    float* out = (float*)d_out;
    float* dumpG = (float*)d_ws;

    gru_pipe10<<<1, 256, 0, stream>>>(X,
                                      enc_w_ih, enc_w_hh, enc_b_ih, enc_b_hh,
                                      dec_w_ih, dec_w_hh, dec_b_ih, dec_b_hh,
                                      out, dumpG);
}